// Round 15
// baseline (66.892 us; speedup 1.0000x reference)
//
#include <hip/hip_runtime.h>

#define T_WPAD  962048   // reflect-padded waveform length (before zero tail)
#define T_RAW   960000
#define NFRM    1879
#define OUTW    1876
#define MEDLEN  1864
#define WINL    30
#define PADL    14
#define FPB     8        // frames per block
#define NBX     235      // ceil(NFRM / FPB)
#define XLEN    4296     // 7*512 + 705 + pad (float4-divisible)
#define X4LEN   1074

typedef float f2 __attribute__((ext_vector_type(2)));

// One packed fp32 FMA: d.lo += a.lo*b.lo, d.hi += a.hi*b.hi (IEEE fp32 each).
__device__ __forceinline__ void pkfma(f2& d, f2 a, f2 b) {
    asm("v_pk_fma_f32 %0, %1, %2, %0" : "+v"(d) : "v"(a), "v"(b));
}

// Body at rotation offset O (0/4/8/12). Window kept as aligned pairs
// Wp[j]=(w2j,w2j+1) and shifted pairs Ws[j]=(w2j+1,w2j+2) so every
// consecutive-element pair is a ready VOP3P operand. Per body:
// 24 v_pk_fma_f32 (= 48 FMAs) + 2 ds_read_b128 + 4 partial-pair movs.
// acc2[r] = (accP[r], accQ[r]): even steps (A.x,A.z) in lo, odd (A.y,A.w) hi.
#define PKBODY(O, AU, AL, K, DO_Q, DO_LD)                                       \
    {                                                                           \
        float4 nx;                                                              \
        if (DO_LD) { AL = X4[aK + (K) + 1]; nx = X4[wBase + (K) + 4]; }         \
        f2 axy; axy.x = AU.x; axy.y = AU.y;                                     \
        f2 azw; azw.x = AU.z; azw.y = AU.w;                                     \
        _Pragma("unroll")                                                       \
        for (int t = 0; t < 6; ++t) {                                           \
            const int r0 = 2 * t, r1 = 2 * t + 1;                               \
            pkfma(acc2[r0], axy, Ws[(((O) + r0 + 1) & 15) >> 1]);               \
            pkfma(acc2[r0], azw, Ws[(((O) + r0 + 3) & 15) >> 1]);               \
            pkfma(acc2[r1], axy, Wp[(((O) + r1 + 1) & 15) >> 1]);               \
            pkfma(acc2[r1], azw, Wp[(((O) + r1 + 3) & 15) >> 1]);               \
        }                                                                       \
        if (DO_Q) {                                                             \
            float qq = fmaf(nx.x, nx.x, fmaf(nx.y, nx.y,                        \
                        fmaf(nx.z, nx.z, nx.w * nx.w)));                        \
            Tcur += (double)qq;                                                 \
        }                                                                       \
        if (DO_LD) {                                                            \
            f2 p0; p0.x = nx.x; p0.y = nx.y;                                    \
            f2 p1; p1.x = nx.z; p1.y = nx.w;                                    \
            f2 ps; ps.x = nx.y; ps.y = nx.z;                                    \
            Wp[((((O) >> 1)) + 0) & 7] = p0;                                    \
            Wp[((((O) >> 1)) + 1) & 7] = p1;                                    \
            Ws[(((O) + 14) & 15) >> 1].y = nx.x;                                \
            Ws[(((O) >> 1)) & 7]         = ps;                                  \
            Ws[(((O) + 2) & 15) >> 1].x  = nx.w;                                \
        }                                                                       \
    }

// ---------------- Kernel 1: NCCF + per-frame lag selection ----------------
// 128 thr = 2 waves; each wave handles FOUR frames (one per 16-lane group).
// g = lane>>4 picks frame-in-wave, s = lane&15 owns lags 12s+1..12s+12.
// Norms in-stream (f64 running quad-sums); LDS = signal tile only.
__global__ __launch_bounds__(128) void nccf_kernel(const float* __restrict__ wav,
                                                   int* __restrict__ idxArr) {
    const int bx   = blockIdx.x;
    const int b    = blockIdx.y;
    const int tid  = threadIdx.x;
    const int wave = tid >> 6;           // 0..1
    const int lane = tid & 63;
    const int g    = lane >> 4;          // frame within wave (0..3)
    const int s    = lane & 15;          // lag-group lane (0..15)

    __shared__ __align__(16) float X[XLEN];

    const long a0 = (long)bx * (FPB * 512);
    const float* wrow = wav + (long)b * T_RAW;

    // Stage wp[a0 .. a0+XLEN): vectorized fast path for interior blocks.
    if (bx >= 1 && bx <= NBX - 2) {
        const float4* src = (const float4*)(wrow + (a0 - 1024));
        float4* dst = (float4*)X;
        for (int i = tid; i < X4LEN; i += 128) dst[i] = src[i];
    } else {
        for (int i = tid; i < XLEN; i += 128) {
            float v = 0.0f;
            long t = a0 + i;
            if (t < T_WPAD) {
                long u = t - 1024;
                if (u < 0) u = -u;
                if (u >= T_RAW) u = 2L * (T_RAW - 1) - u;
                v = wrow[u];
            }
            X[i] = v;
        }
    }
    __syncthreads();

    const int F  = wave * 4 + g;         // frame within block (0..7)
    const int gf = bx * FPB + F;         // global frame
    const bool valid = (gf < NFRM);

    f2 acc2[12];
    #pragma unroll
    for (int r = 0; r < 12; ++r) { acc2[r].x = 0.0f; acc2[r].y = 0.0f; }
    float sq[12];                         // X[12s+j]^2, j=0..11
    double Tcur = 0.0;

    f2 Wp[8], Ws[8];
    float4 Aev, Aod;
    const float4* X4 = (const float4*)X;
    const int aK    = F * 128;            // float4 index of Xf[0]
    const int wBase = aK + 3 * s;         // float4 index of Xf[12s]

    {   // Prologue: window contents 0..15 as aligned + shifted pairs.
        float4 q0 = X4[wBase + 0], q1 = X4[wBase + 1];
        float4 q2 = X4[wBase + 2], q3 = X4[wBase + 3];
        Wp[0].x=q0.x; Wp[0].y=q0.y;  Wp[1].x=q0.z; Wp[1].y=q0.w;
        Wp[2].x=q1.x; Wp[2].y=q1.y;  Wp[3].x=q1.z; Wp[3].y=q1.w;
        Wp[4].x=q2.x; Wp[4].y=q2.y;  Wp[5].x=q2.z; Wp[5].y=q2.w;
        Wp[6].x=q3.x; Wp[6].y=q3.y;  Wp[7].x=q3.z; Wp[7].y=q3.w;
        Ws[0].x=q0.y; Ws[0].y=q0.z;  Ws[1].x=q0.w; Ws[1].y=q1.x;
        Ws[2].x=q1.y; Ws[2].y=q1.z;  Ws[3].x=q1.w; Ws[3].y=q2.x;
        Ws[4].x=q2.y; Ws[4].y=q2.z;  Ws[5].x=q2.w; Ws[5].y=q3.x;
        Ws[6].x=q3.y; Ws[6].y=q3.z;  Ws[7].x=q3.w; Ws[7].y=q0.x;
        sq[0]=q0.x*q0.x; sq[1]=q0.y*q0.y; sq[2] =q0.z*q0.z; sq[3] =q0.w*q0.w;
        sq[4]=q1.x*q1.x; sq[5]=q1.y*q1.y; sq[6] =q1.z*q1.z; sq[7] =q1.w*q1.w;
        sq[8]=q2.x*q2.x; sq[9]=q2.y*q2.y; sq[10]=q2.z*q2.z; sq[11]=q2.w*q2.w;
        #pragma unroll
        for (int j = 0; j < 12; ++j) Tcur += (double)sq[j];
        Tcur += (double)(q3.x*q3.x); Tcur += (double)(q3.y*q3.y);
        Tcur += (double)(q3.z*q3.z); Tcur += (double)(q3.w*q3.w);   // T(16)
        Aev = X4[aK];                     // A content 0
    }

    // Main: groups of 4 bodies (O = 0,4,8,12), bodies 0..123 with T quads.
    for (int kg = 0; kg < 31; ++kg) {
        const int k4 = kg * 4;
        PKBODY(0,  Aev, Aod, k4 + 0, 1, 1)
        PKBODY(4,  Aod, Aev, k4 + 1, 1, 1)
        PKBODY(8,  Aev, Aod, k4 + 2, 1, 1)
        PKBODY(12, Aod, Aev, k4 + 3, 1, 1)
    }
    const double T512 = Tcur;             // T(512) after body 123
    // Tail: bodies 124..126 load (window contents through 523, A through 127),
    // body 127 pure compute.
    PKBODY(0,  Aev, Aod, 124, 0, 1)
    PKBODY(4,  Aod, Aev, 125, 0, 1)
    PKBODY(8,  Aev, Aod, 126, 0, 1)
    PKBODY(12, Aod, Aod, 127, 0, 0)

    // Trailing elements X[12s+512..524) live in slots 0..11 = Wp[0..5].
    float trail[12];
    #pragma unroll
    for (int j = 0; j < 6; ++j) { trail[2*j] = Wp[j].x; trail[2*j+1] = Wp[j].y; }

    // Epilogue: per-lag norms. q(r) = T(512+r) - T(r).
    double qv[12];
    {
        double Thi = T512, Tlo = 0.0;
        #pragma unroll
        for (int r = 1; r <= 12; ++r) {
            float eh = trail[r - 1];          // X[12s+512+(r-1)]
            Thi += (double)(eh * eh);
            Tlo += (double)sq[r - 1];
            qv[r - 1] = Thi - Tlo;
        }
    }
    double s1d = __shfl(T512, 0, 16);         // frame sumsq P[512] (s=0 lane)

    // Per-lane selection over its 12 lags (fp32, np-like first-max ties).
    float bestv = -1e30f, halfv = -1e30f;
    int bestk = 1 << 30, halfk = 1 << 30;
    {
        float s1 = 1e-9f + sqrtf((float)s1d);
        float s1n = s1 * s1;
        #pragma unroll
        for (int r = 1; r <= 12; ++r) {
            int lag  = 12 * s + r;
            int kidx = lag - 1;               // nccf lag index 0..191
            if (kidx <= 188) {
                float s2 = 1e-9f + sqrtf((float)qv[r - 1]);
                float v  = (acc2[r - 1].x + acc2[r - 1].y) / s1n / (s2 * s2);
                if (kidx >= 5) {
                    if (v > bestv) { bestv = v; bestk = kidx; }
                    if (kidx <= 93 && v > halfv) { halfv = v; halfk = kidx; }
                }
            }
        }
    }

    // 16-lane (max, first-argmax) reduction for both slices.
    #pragma unroll
    for (int off = 8; off >= 1; off >>= 1) {
        float ov = __shfl_xor(bestv, off, 16); int ok = __shfl_xor(bestk, off, 16);
        if (ov > bestv || (ov == bestv && ok < bestk)) { bestv = ov; bestk = ok; }
        float hv = __shfl_xor(halfv, off, 16); int hk = __shfl_xor(halfk, off, 16);
        if (hv > halfv || (hv == halfv && hk < halfk)) { halfv = hv; halfk = hk; }
    }

    if (valid && s == 0) {
        bool m = (halfv > 0.99f * bestv);
        int sel = m ? halfk : bestk;
        idxArr[b * NFRM + gf] = sel + 1;      // = chosen lag
    }
}

// ---------------- Kernel 2: 30-wide median filter + pitch ----------------
__global__ __launch_bounds__(256) void med_kernel(const int* __restrict__ idxArr,
                                                  float* __restrict__ out) {
    int gid = blockIdx.x * 256 + threadIdx.x;
    if (gid >= 8 * OUTW) return;
    int b = gid / OUTW;
    int i = gid - b * OUTW;
    float o = 0.0f;
    if (i < MEDLEN) {
        const int* row = idxArr + b * NFRM;
        int vals[WINL];
        #pragma unroll
        for (int m = 0; m < WINL; ++m) {
            int sIdx = i + m - PADL;          // left pad = repeat idx[0]
            vals[m] = row[sIdx < 0 ? 0 : sIdx];
        }
        int med = vals[0];
        #pragma unroll
        for (int c = 0; c < WINL; ++c) {
            int cl = 0, ce = 0;
            #pragma unroll
            for (int m = 0; m < WINL; ++m) {
                cl += (vals[m] <  vals[c]) ? 1 : 0;
                ce += (vals[m] == vals[c]) ? 1 : 0;
            }
            if (cl <= 14 && 14 < cl + ce) med = vals[c];   // rank-14 = sorted[14]
        }
        o = 16000.0f / (1e-9f + (float)med);
    }
    out[gid] = o;
}

extern "C" void kernel_launch(void* const* d_in, const int* in_sizes, int n_in,
                              void* d_out, int out_size, void* d_ws, size_t ws_size,
                              hipStream_t stream) {
    const float* wav = (const float*)d_in[0];
    float* out = (float*)d_out;
    int* idxArr = (int*)d_ws;                 // 8*1879 ints = 60128 B

    dim3 gB(NBX, 8);                          // 235 x 8 blocks, 8 frames each
    hipLaunchKernelGGL(nccf_kernel, gB, dim3(128), 0, stream, wav, idxArr);

    int total = 8 * OUTW;
    hipLaunchKernelGGL(med_kernel, dim3((total + 255) / 256), dim3(256), 0, stream,
                       idxArr, out);
}

// Round 16
// 61.895 us; speedup vs baseline: 1.0807x; 1.0807x over previous
//
#include <hip/hip_runtime.h>

#define T_WPAD  962048   // reflect-padded waveform length (before zero tail)
#define T_RAW   960000
#define NFRM    1879
#define OUTW    1876
#define MEDLEN  1864
#define WINL    30
#define PADL    14
#define FPB     4        // frames per block
#define NBX     470      // ceil(NFRM / FPB)
#define XLEN    2244     // 3*512 + 705 + pad (float4-divisible)
#define X4LEN   561

// Rotated inner body (R13-proven): window offset O (0/4/8/12), all indices
// compile-time. Reads w[(O+1)..(O+15) mod 16]; loads content k+4 into the
// retiring slots w[O..O+3]; loads A(k+1). 2 ds_read_b128 + 48 fmaf, nothing else.
#define NCCF_BODY(O, AUSE, ALOAD, K)                                            \
    {                                                                           \
        ALOAD = X4[aK + (K) + 1];                                               \
        float4 nx = X4[wBase + (K) + 4];                                        \
        _Pragma("unroll")                                                       \
        for (int r = 0; r < 12; ++r) {                                          \
            acc[r] = fmaf(AUSE.x, w[(O + r + 1) & 15], acc[r]);                 \
            acc[r] = fmaf(AUSE.y, w[(O + r + 2) & 15], acc[r]);                 \
            acc[r] = fmaf(AUSE.z, w[(O + r + 3) & 15], acc[r]);                 \
            acc[r] = fmaf(AUSE.w, w[(O + r + 4) & 15], acc[r]);                 \
        }                                                                       \
        w[(O + 0) & 15] = nx.x; w[(O + 1) & 15] = nx.y;                         \
        w[(O + 2) & 15] = nx.z; w[(O + 3) & 15] = nx.w;                         \
    }

// ---------------- Kernel 1: NCCF + per-frame lag selection ----------------
// 64 thr = 1 wave per block; wave handles FOUR frames (one per 16-lane group).
// g = lane>>4 picks frame, s = lane&15 owns lags 12s+1..12s+12.
// Inner loop: ONLY 2 ds_read_b128 + 48 fmaf per body (T-tracking removed).
// Norms: cooperative f64 frame-norm T0 (prologue reduce) + per-lane T_s(512)
// via neighbor recurrence T_{s+1} = T_s - L_s + R_s resolved by a width-16
// shuffle scan in the epilogue (L_s/R_s from registers already needed for qv).
__global__ __launch_bounds__(64) void nccf_kernel(const float* __restrict__ wav,
                                                  int* __restrict__ idxArr) {
    const int bx   = blockIdx.x;
    const int b    = blockIdx.y;
    const int tid  = threadIdx.x;
    const int lane = tid & 63;
    const int g    = lane >> 4;          // frame within block (0..3)
    const int s    = lane & 15;          // lag-group lane (0..15)

    __shared__ __align__(16) float X[XLEN];

    const long a0 = (long)bx * (FPB * 512);
    const float* wrow = wav + (long)b * T_RAW;

    // Stage wp[a0 .. a0+XLEN): vectorized fast path for interior blocks.
    if (bx >= 1 && bx <= NBX - 2) {
        const float4* src = (const float4*)(wrow + (a0 - 1024));
        float4* dst = (float4*)X;
        for (int i = tid; i < X4LEN; i += 64) dst[i] = src[i];
    } else {
        for (int i = tid; i < XLEN; i += 64) {
            float v = 0.0f;
            long t = a0 + i;
            if (t < T_WPAD) {
                long u = t - 1024;
                if (u < 0) u = -u;
                if (u >= T_RAW) u = 2L * (T_RAW - 1) - u;
                v = wrow[u];
            }
            X[i] = v;
        }
    }
    __syncthreads();

    const int F  = g;                    // frame within block
    const int gf = bx * FPB + F;         // global frame
    const bool valid = (gf < NFRM);

    const float4* X4 = (const float4*)X;
    const int aK    = F * 128;           // float4 index of Xf[0]
    const int wBase = aK + 3 * s;        // float4 index of Xf[12s]

    // Cooperative frame norm T0 = sumsq X[F*512 .. F*512+512), f64.
    double T0 = 0.0;
    {
        const float4* fb = X4 + aK + 8 * s;
        #pragma unroll
        for (int m = 0; m < 8; ++m) {
            float4 v4 = fb[m];
            T0 += (double)v4.x * v4.x; T0 += (double)v4.y * v4.y;
            T0 += (double)v4.z * v4.z; T0 += (double)v4.w * v4.w;
        }
        #pragma unroll
        for (int off = 8; off >= 1; off >>= 1) T0 += __shfl_xor(T0, off, 16);
    }

    float acc[12];
    #pragma unroll
    for (int r = 0; r < 12; ++r) acc[r] = 0.0f;
    float sq[12];                        // X[12s+j]^2, j=0..11
    float w[16];
    float4 Aev, Aod;

    {   // Prologue: window contents 0..15; A content 0.
        #pragma unroll
        for (int d = 0; d < 4; ++d) {
            float4 t4 = X4[wBase + d];
            w[4*d] = t4.x; w[4*d+1] = t4.y; w[4*d+2] = t4.z; w[4*d+3] = t4.w;
        }
        #pragma unroll
        for (int j = 0; j < 12; ++j) sq[j] = w[j] * w[j];
        Aev = X4[aK];
    }

    // Main loop: 32 uniform groups of 4 bodies (k = 0..127). All loads
    // in-bounds by tile construction (max f4 idx wBase+131 <= 560).
    #pragma unroll 2
    for (int kg = 0; kg < 32; ++kg) {
        const int k4 = kg * 4;
        NCCF_BODY(0,  Aev, Aod, k4 + 0)
        NCCF_BODY(4,  Aod, Aev, k4 + 1)
        NCCF_BODY(8,  Aev, Aod, k4 + 2)
        NCCF_BODY(12, Aod, Aev, k4 + 3)
    }
    // w[0..11] = X[12s+512 .. 12s+524) (trailing elements).

    // Epilogue: per-lane T_s(512) via neighbor recurrence + shuffle scan.
    //   L_s = sumsq X[12s..12s+12), R_s = sumsq X[12s+512..12s+524)
    //   T_s = T0 + sum_{u<s} (R_u - L_u)
    double Lsum = 0.0, Rsum = 0.0;
    #pragma unroll
    for (int j = 0; j < 12; ++j) {
        Lsum += (double)sq[j];
        Rsum += (double)w[j] * w[j];
    }
    double D = Rsum - Lsum, inc = D;
    #pragma unroll
    for (int off = 1; off < 16; off <<= 1) {
        double v = __shfl_up(inc, off, 16);
        if (s >= off) inc += v;
    }
    const double Ts = T0 + (inc - D);     // T_s(512)

    // Per-lag norms: q(r) = T_s(512+r) - T_s(r).
    double qv[12];
    {
        double Thi = Ts, Tlo = 0.0;
        #pragma unroll
        for (int r = 1; r <= 12; ++r) {
            float eh = w[r - 1];          // X[12s+512+(r-1)]
            Thi += (double)eh * eh;
            Tlo += (double)sq[r - 1];
            qv[r - 1] = Thi - Tlo;
        }
    }

    // Per-lane selection over its 12 lags (fp32, np-like first-max ties).
    float bestv = -1e30f, halfv = -1e30f;
    int bestk = 1 << 30, halfk = 1 << 30;
    {
        float s1 = 1e-9f + sqrtf((float)T0);
        float s1n = s1 * s1;
        #pragma unroll
        for (int r = 1; r <= 12; ++r) {
            int lag  = 12 * s + r;
            int kidx = lag - 1;           // nccf lag index 0..191
            if (kidx <= 188) {
                float s2 = 1e-9f + sqrtf((float)qv[r - 1]);
                float v  = acc[r - 1] / s1n / (s2 * s2);
                if (kidx >= 5) {
                    if (v > bestv) { bestv = v; bestk = kidx; }
                    if (kidx <= 93 && v > halfv) { halfv = v; halfk = kidx; }
                }
            }
        }
    }

    // 16-lane (max, first-argmax) reduction for both slices.
    #pragma unroll
    for (int off = 8; off >= 1; off >>= 1) {
        float ov = __shfl_xor(bestv, off, 16); int ok = __shfl_xor(bestk, off, 16);
        if (ov > bestv || (ov == bestv && ok < bestk)) { bestv = ov; bestk = ok; }
        float hv = __shfl_xor(halfv, off, 16); int hk = __shfl_xor(halfk, off, 16);
        if (hv > halfv || (hv == halfv && hk < halfk)) { halfv = hv; halfk = hk; }
    }

    if (valid && s == 0) {
        bool m = (halfv > 0.99f * bestv);
        int sel = m ? halfk : bestk;
        idxArr[b * NFRM + gf] = sel + 1;  // = chosen lag
    }
}

// ---------------- Kernel 2: 30-wide median filter + pitch ----------------
__global__ __launch_bounds__(256) void med_kernel(const int* __restrict__ idxArr,
                                                  float* __restrict__ out) {
    int gid = blockIdx.x * 256 + threadIdx.x;
    if (gid >= 8 * OUTW) return;
    int b = gid / OUTW;
    int i = gid - b * OUTW;
    float o = 0.0f;
    if (i < MEDLEN) {
        const int* row = idxArr + b * NFRM;
        int vals[WINL];
        #pragma unroll
        for (int m = 0; m < WINL; ++m) {
            int sIdx = i + m - PADL;      // left pad = repeat idx[0]
            vals[m] = row[sIdx < 0 ? 0 : sIdx];
        }
        int med = vals[0];
        #pragma unroll
        for (int c = 0; c < WINL; ++c) {
            int cl = 0, ce = 0;
            #pragma unroll
            for (int m = 0; m < WINL; ++m) {
                cl += (vals[m] <  vals[c]) ? 1 : 0;
                ce += (vals[m] == vals[c]) ? 1 : 0;
            }
            if (cl <= 14 && 14 < cl + ce) med = vals[c];   // rank-14 = sorted[14]
        }
        o = 16000.0f / (1e-9f + (float)med);
    }
    out[gid] = o;
}

extern "C" void kernel_launch(void* const* d_in, const int* in_sizes, int n_in,
                              void* d_out, int out_size, void* d_ws, size_t ws_size,
                              hipStream_t stream) {
    const float* wav = (const float*)d_in[0];
    float* out = (float*)d_out;
    int* idxArr = (int*)d_ws;             // 8*1879 ints = 60128 B

    dim3 gB(NBX, 8);                      // 470 x 8 one-wave blocks, 4 frames each
    hipLaunchKernelGGL(nccf_kernel, gB, dim3(64), 0, stream, wav, idxArr);

    int total = 8 * OUTW;
    hipLaunchKernelGGL(med_kernel, dim3((total + 255) / 256), dim3(256), 0, stream,
                       idxArr, out);
}